// Round 1
// baseline (21.858 us; speedup 1.0000x reference)
//
#include <hip/hip_runtime.h>
#include <math.h>

#define M_SAMPLES 131072
#define NBLK 512
#define BLK 256

__device__ __forceinline__ float logaddexp_f(float a, float b) {
    float m = fmaxf(a, b);
    if (m == -INFINITY) return -INFINITY;
    float d = fminf(a, b) - m;
    return m + log1pf(expf(d));
}

__global__ __launch_bounds__(BLK) void bez_main_kernel(
    const float* __restrict__ P0, const float* __restrict__ Pd,
    const float* __restrict__ Pmid, const float* __restrict__ ts,
    float* __restrict__ partial)
{
    __shared__ float sP[8][8][2];
    __shared__ float sQ[7][8][2];
    __shared__ float sR[6][8][2];
    __shared__ float red[4][3];

    const int tid = threadIdx.x;
    if (tid < 16) { sP[0][tid >> 1][tid & 1] = P0[tid]; sP[7][tid >> 1][tid & 1] = Pd[tid]; }
    if (tid < 96) { int r = tid / 16, rem = tid % 16; sP[1 + r][rem >> 1][rem & 1] = Pmid[tid]; }
    __syncthreads();
    if (tid < 112) {
        int k = tid / 16, rem = tid % 16, j = rem >> 1, c = rem & 1;
        sQ[k][j][c] = 7.f * (sP[k + 1][j][c] - sP[k][j][c]);
    }
    __syncthreads();
    if (tid < 96) {
        int k = tid / 16, rem = tid % 16, j = rem >> 1, c = rem & 1;
        sR[k][j][c] = 6.f * (sQ[k + 1][j][c] - sQ[k][j][c]);
    }
    __syncthreads();

    const int gid = blockIdx.x * BLK + tid;
    const float t = ts[gid];
    const float u = 1.f - t;
    float tp[8], up[8];
    tp[0] = 1.f; up[0] = 1.f;
#pragma unroll
    for (int k = 1; k < 8; ++k) { tp[k] = tp[k - 1] * t; up[k] = up[k - 1] * u; }

    const float C7[8] = {1.f, 7.f, 21.f, 35.f, 35.f, 21.f, 7.f, 1.f};
    const float C6[7] = {1.f, 6.f, 15.f, 20.f, 15.f, 6.f, 1.f};
    const float C5[6] = {1.f, 5.f, 10.f, 10.f, 5.f, 1.f};
    float b7[8], b6[7], b5[6];
#pragma unroll
    for (int k = 0; k < 8; ++k) b7[k] = C7[k] * tp[k] * up[7 - k];
#pragma unroll
    for (int k = 0; k < 7; ++k) b6[k] = C6[k] * tp[k] * up[6 - k];
#pragma unroll
    for (int k = 0; k < 6; ++k) b5[k] = C5[k] * tp[k] * up[5 - k];

    // T: polynomial coefficient samples (8 complex)
    float Tr[8], Ti[8];
#pragma unroll
    for (int j = 0; j < 8; ++j) {
        float ar = 0.f, ai = 0.f;
#pragma unroll
        for (int k = 0; k < 8; ++k) { ar += b7[k] * sP[k][j][0]; ai += b7[k] * sP[k][j][1]; }
        Tr[j] = ar; Ti[j] = ai;
    }
    // speed^2 from first derivative (degree-6 Bezier of sQ)
    float sp2 = 0.f;
#pragma unroll
    for (int j = 0; j < 8; ++j) {
        float ar = 0.f, ai = 0.f;
#pragma unroll
        for (int k = 0; k < 7; ++k) { ar += b6[k] * sQ[k][j][0]; ai += b6[k] * sQ[k][j][1]; }
        sp2 += ar * ar + ai * ai;
    }
    // accel^2 from second derivative (degree-5 Bezier of sR)
    float ac2 = 0.f;
#pragma unroll
    for (int j = 0; j < 8; ++j) {
        float ar = 0.f, ai = 0.f;
#pragma unroll
        for (int k = 0; k < 6; ++k) { ar += b5[k] * sR[k][j][0]; ai += b5[k] * sR[k][j][1]; }
        ac2 += ar * ar + ai * ai;
    }
    const float speed = sqrtf(sp2);

    // Ascending-order coefficients: f_j = pc_{7-j} (j=0..7), f_8 = 1 (monic).
    float fr[9], fi[9];
#pragma unroll
    for (int j = 0; j < 8; ++j) { fr[j] = Tr[7 - j]; fi[j] = Ti[7 - j]; }
    fr[8] = 1.f; fi[8] = 0.f;
    // g = f' ascending: g_j = (j+1) f_{j+1}, g_8 = 0
    float gr[9], gi[9];
#pragma unroll
    for (int j = 0; j < 8; ++j) { gr[j] = (float)(j + 1) * fr[j + 1]; gi[j] = (float)(j + 1) * fi[j + 1]; }
    gr[8] = 0.f; gi[8] = 0.f;

    // Bezout matrix B (8x8 complex): |det B| = |Res(f, f')| = |det Sylvester| (f monic).
    // Recurrence: B[7][j] = f8*g_j - f_j*g8 = g_j ; B[i-1][j] = (f_i g_j - f_j g_i) + B[i][j-1]
    float Br[8][8], Bi[8][8];
#pragma unroll
    for (int j = 0; j < 8; ++j) { Br[7][j] = gr[j]; Bi[7][j] = gi[j]; }
#pragma unroll
    for (int i = 7; i >= 1; --i) {
#pragma unroll
        for (int j = 0; j < 8; ++j) {
            float cr = (fr[i] * gr[j] - fi[i] * gi[j]) - (fr[j] * gr[i] - fi[j] * gi[i]);
            float ci = (fr[i] * gi[j] + fi[i] * gr[j]) - (fr[j] * gi[i] + fi[j] * gr[i]);
            if (j >= 1) { cr += Br[i][j - 1]; ci += Bi[i][j - 1]; }
            Br[i - 1][j] = cr; Bi[i - 1][j] = ci;
        }
    }

    // In-register complex LU with partial pivoting (compare-swap chain, static idx).
    float logdet = 0.f;
#pragma unroll
    for (int k = 0; k < 8; ++k) {
#pragma unroll
        for (int i = k + 1; i < 8; ++i) {
            float mk = Br[k][k] * Br[k][k] + Bi[k][k] * Bi[k][k];
            float mi2 = Br[i][k] * Br[i][k] + Bi[i][k] * Bi[i][k];
            bool sw = mi2 > mk;
#pragma unroll
            for (int j = k; j < 8; ++j) {
                float a = Br[k][j], b = Br[i][j];
                Br[k][j] = sw ? b : a; Br[i][j] = sw ? a : b;
                float c = Bi[k][j], d = Bi[i][j];
                Bi[k][j] = sw ? d : c; Bi[i][j] = sw ? c : d;
            }
        }
        float pr = Br[k][k], pi = Bi[k][k];
        float pm2 = pr * pr + pi * pi;
        logdet += 0.5f * logf(pm2);       // log|pivot|; log(0) = -inf is clamped below
        float inv = (pm2 > 1e-37f) ? 1.f / pm2 : 0.f;
#pragma unroll
        for (int i = k + 1; i < 8; ++i) {
            float mr = (Br[i][k] * pr + Bi[i][k] * pi) * inv;
            float mi_ = (Bi[i][k] * pr - Br[i][k] * pi) * inv;
#pragma unroll
            for (int j = k + 1; j < 8; ++j) {
                float br = Br[k][j], bi2 = Bi[k][j];
                Br[i][j] -= mr * br - mi_ * bi2;
                Bi[i][j] -= mr * bi2 + mi_ * br;
            }
        }
    }

    const float LOG_DISC_EPS = -27.63102111592855f;   // ln 1e-12
    const float LOG_DELTA2  = -27.63102111592855f;    // 2 ln 1e-6
    const float LOG1P_LEAD  = 1e-12f;                 // log(1 + 1e-12)
    float disc_logabs = logaddexp_f(logdet, LOG_DISC_EPS) - LOG1P_LEAD;
    float log_softabs = 0.5f * logaddexp_f(2.f * disc_logabs, LOG_DELTA2);
    float log_softabs_eps = logaddexp_f(log_softabs, LOG_DISC_EPS);
    float w = expf(-log_softabs_eps * 0.125f);        // /N_DEG = /8

    float v1 = speed * w, v2 = sp2, v3 = ac2;
#pragma unroll
    for (int off = 32; off; off >>= 1) {
        v1 += __shfl_down(v1, off);
        v2 += __shfl_down(v2, off);
        v3 += __shfl_down(v3, off);
    }
    const int wid = tid >> 6, lane = tid & 63;
    if (lane == 0) { red[wid][0] = v1; red[wid][1] = v2; red[wid][2] = v3; }
    __syncthreads();
    if (tid == 0) {
        float s1 = 0.f, s2 = 0.f, s3 = 0.f;
        for (int w2 = 0; w2 < 4; ++w2) { s1 += red[w2][0]; s2 += red[w2][1]; s3 += red[w2][2]; }
        partial[blockIdx.x * 3 + 0] = s1;
        partial[blockIdx.x * 3 + 1] = s2;
        partial[blockIdx.x * 3 + 2] = s3;
    }
}

__global__ __launch_bounds__(NBLK) void bez_finalize_kernel(
    const float* __restrict__ partial, float* __restrict__ out)
{
    const int tid = threadIdx.x;
    float v1 = partial[tid * 3 + 0];
    float v2 = partial[tid * 3 + 1];
    float v3 = partial[tid * 3 + 2];
#pragma unroll
    for (int off = 32; off; off >>= 1) {
        v1 += __shfl_down(v1, off);
        v2 += __shfl_down(v2, off);
        v3 += __shfl_down(v3, off);
    }
    __shared__ float red[8][3];
    const int wid = tid >> 6, lane = tid & 63;
    if (lane == 0) { red[wid][0] = v1; red[wid][1] = v2; red[wid][2] = v3; }
    __syncthreads();
    if (tid == 0) {
        float s1 = 0.f, s2 = 0.f, s3 = 0.f;
        for (int w2 = 0; w2 < 8; ++w2) { s1 += red[w2][0]; s2 += red[w2][1]; s3 += red[w2][2]; }
        const float Mf = (float)M_SAMPLES;
        out[0] = s1 / Mf + 0.1f * sqrtf(s2 / Mf) + 0.01f * sqrtf(s3 / Mf);
    }
}

extern "C" void kernel_launch(void* const* d_in, const int* in_sizes, int n_in,
                              void* d_out, int out_size, void* d_ws, size_t ws_size,
                              hipStream_t stream) {
    const float* P0   = (const float*)d_in[0];   // (8,2)
    const float* Pd   = (const float*)d_in[1];   // (8,2)
    const float* Pmid = (const float*)d_in[2];   // (6,8,2)
    const float* ts   = (const float*)d_in[3];   // (131072,)
    float* out = (float*)d_out;
    float* partial = (float*)d_ws;               // NBLK*3 floats

    bez_main_kernel<<<NBLK, BLK, 0, stream>>>(P0, Pd, Pmid, ts, partial);
    bez_finalize_kernel<<<1, NBLK, 0, stream>>>(partial, out);
}

// Round 2
// 16.119 us; speedup vs baseline: 1.3561x; 1.3561x over previous
//
#include <hip/hip_runtime.h>
#include <math.h>

#define M_SAMPLES 131072
#define NBLK 512
#define BLK 256

__device__ __forceinline__ float logaddexp_f(float a, float b) {
    float m = fmaxf(a, b);
    if (m == -INFINITY) return -INFINITY;
    float d = fminf(a, b) - m;
    return m + __logf(1.f + __expf(d));
}

__global__ __launch_bounds__(BLK) void bez_main_kernel(
    const float* __restrict__ P0, const float* __restrict__ Pd,
    const float* __restrict__ Pmid, const float* __restrict__ ts,
    float* __restrict__ partial)
{
    __shared__ float sP[8][8][2];
    __shared__ float sQ[7][8][2];
    __shared__ float sR[6][8][2];
    __shared__ float red[4][3];

    const int tid = threadIdx.x;
    if (tid < 16) { sP[0][tid >> 1][tid & 1] = P0[tid]; sP[7][tid >> 1][tid & 1] = Pd[tid]; }
    if (tid < 96) { int r = tid / 16, rem = tid % 16; sP[1 + r][rem >> 1][rem & 1] = Pmid[tid]; }
    __syncthreads();
    if (tid < 112) {
        int k = tid / 16, rem = tid % 16, j = rem >> 1, c = rem & 1;
        sQ[k][j][c] = 7.f * (sP[k + 1][j][c] - sP[k][j][c]);
    }
    __syncthreads();
    if (tid < 96) {
        int k = tid / 16, rem = tid % 16, j = rem >> 1, c = rem & 1;
        sR[k][j][c] = 6.f * (sQ[k + 1][j][c] - sQ[k][j][c]);
    }
    __syncthreads();

    const int gid = blockIdx.x * BLK + tid;
    const float t = ts[gid];
    const float u = 1.f - t;
    float tp[8], up[8];
    tp[0] = 1.f; up[0] = 1.f;
#pragma unroll
    for (int k = 1; k < 8; ++k) { tp[k] = tp[k - 1] * t; up[k] = up[k - 1] * u; }

    const float C7[8] = {1.f, 7.f, 21.f, 35.f, 35.f, 21.f, 7.f, 1.f};
    const float C6[7] = {1.f, 6.f, 15.f, 20.f, 15.f, 6.f, 1.f};
    const float C5[6] = {1.f, 5.f, 10.f, 10.f, 5.f, 1.f};
    float b7[8], b6[7], b5[6];
#pragma unroll
    for (int k = 0; k < 8; ++k) b7[k] = C7[k] * tp[k] * up[7 - k];
#pragma unroll
    for (int k = 0; k < 7; ++k) b6[k] = C6[k] * tp[k] * up[6 - k];
#pragma unroll
    for (int k = 0; k < 6; ++k) b5[k] = C5[k] * tp[k] * up[5 - k];

    // T: polynomial coefficient samples (8 complex)
    float Tr[8], Ti[8];
#pragma unroll
    for (int j = 0; j < 8; ++j) {
        float ar = 0.f, ai = 0.f;
#pragma unroll
        for (int k = 0; k < 8; ++k) { ar += b7[k] * sP[k][j][0]; ai += b7[k] * sP[k][j][1]; }
        Tr[j] = ar; Ti[j] = ai;
    }
    // speed^2 from first derivative (degree-6 Bezier of sQ)
    float sp2 = 0.f;
#pragma unroll
    for (int j = 0; j < 8; ++j) {
        float ar = 0.f, ai = 0.f;
#pragma unroll
        for (int k = 0; k < 7; ++k) { ar += b6[k] * sQ[k][j][0]; ai += b6[k] * sQ[k][j][1]; }
        sp2 += ar * ar + ai * ai;
    }
    // accel^2 from second derivative (degree-5 Bezier of sR)
    float ac2 = 0.f;
#pragma unroll
    for (int j = 0; j < 8; ++j) {
        float ar = 0.f, ai = 0.f;
#pragma unroll
        for (int k = 0; k < 6; ++k) { ar += b5[k] * sR[k][j][0]; ai += b5[k] * sR[k][j][1]; }
        ac2 += ar * ar + ai * ai;
    }
    const float speed = sqrtf(sp2);

    // Ascending-order coefficients: f_j = pc_{7-j} (j=0..7), f_8 = 1 (monic).
    float fr[9], fi[9];
#pragma unroll
    for (int j = 0; j < 8; ++j) { fr[j] = Tr[7 - j]; fi[j] = Ti[7 - j]; }
    fr[8] = 1.f; fi[8] = 0.f;
    // g = f' ascending: g_j = (j+1) f_{j+1}, g_8 = 0
    float gr[9], gi[9];
#pragma unroll
    for (int j = 0; j < 8; ++j) { gr[j] = (float)(j + 1) * fr[j + 1]; gi[j] = (float)(j + 1) * fi[j + 1]; }
    gr[8] = 0.f; gi[8] = 0.f;

    // Antisymmetric pair terms c_{ab} = f_a g_b - f_b g_a, only a<b stored.
    float cR[8][8], cI[8][8];
#pragma unroll
    for (int a = 0; a < 8; ++a) {
#pragma unroll
        for (int b = a + 1; b < 8; ++b) {
            cR[a][b] = (fr[a] * gr[b] - fi[a] * gi[b]) - (fr[b] * gr[a] - fi[b] * gi[a]);
            cI[a][b] = (fr[a] * gi[b] + fi[a] * gr[b]) - (fr[b] * gi[a] + fi[b] * gr[a]);
        }
    }

    // Bezout matrix B (8x8 complex symmetric): |det B| = |Res(f,f')| (f monic).
    // B[7][j] = g_j ; B[i-1][j] = c_{ij} + B[i][j-1]
    float Br[8][8], Bi[8][8];
#pragma unroll
    for (int j = 0; j < 8; ++j) { Br[7][j] = gr[j]; Bi[7][j] = gi[j]; }
#pragma unroll
    for (int i = 7; i >= 1; --i) {
#pragma unroll
        for (int j = 0; j < 8; ++j) {
            float cr, ci;
            if (i < j)      { cr = cR[i][j];  ci = cI[i][j]; }
            else if (i > j) { cr = -cR[j][i]; ci = -cI[j][i]; }
            else            { cr = 0.f;       ci = 0.f; }
            if (j >= 1) { cr += Br[i][j - 1]; ci += Bi[i][j - 1]; }
            Br[i - 1][j] = cr; Bi[i - 1][j] = ci;
        }
    }

    // Pivot-free complex-symmetric LDL^T on the upper triangle.
    // det = prod d_k. Guarded against 0/inf pivots; entry clamp sanitizes
    // NaN (fmaxf(NaN,c)=c) and prevents overflow chains.
    float logdet = 0.f;
#pragma unroll
    for (int k = 0; k < 8; ++k) {
        float dr = Br[k][k], di = Bi[k][k];
        float pm2 = dr * dr + di * di;
        logdet += 0.5f * __logf(fminf(fmaxf(pm2, 1e-38f), 1e38f));
        if (k < 7) {
            float is = __builtin_amdgcn_rcpf(pm2);
            bool ok = (pm2 > 1e-30f) && (pm2 < 1e30f);
            is = ok ? is : 0.f;
            float drs = ok ? dr : 0.f, dis = ok ? di : 0.f;
            float ivr = drs * is, ivi = -dis * is;   // 1/d
            float wr[8], wi[8];
#pragma unroll
            for (int i = k + 1; i < 8; ++i) {
                float ar = Br[k][i], ai = Bi[k][i];  // A[i][k] by symmetry
                wr[i] = ar * ivr - ai * ivi;
                wi[i] = ar * ivi + ai * ivr;
            }
#pragma unroll
            for (int i = k + 1; i < 8; ++i) {
#pragma unroll
                for (int j = i; j < 8; ++j) {
                    float br = Br[k][j], bi2 = Bi[k][j];
                    float ur = Br[i][j] - (wr[i] * br - wi[i] * bi2);
                    float ui = Bi[i][j] - (wr[i] * bi2 + wi[i] * br);
                    Br[i][j] = fminf(fmaxf(ur, -1e18f), 1e18f);
                    Bi[i][j] = fminf(fmaxf(ui, -1e18f), 1e18f);
                }
            }
        }
    }

    const float LOG_DISC_EPS = -27.63102111592855f;   // ln 1e-12
    const float LOG_DELTA2  = -27.63102111592855f;    // 2 ln 1e-6
    const float LOG1P_LEAD  = 1e-12f;                 // log(1 + 1e-12)
    float disc_logabs = logaddexp_f(logdet, LOG_DISC_EPS) - LOG1P_LEAD;
    float log_softabs = 0.5f * logaddexp_f(2.f * disc_logabs, LOG_DELTA2);
    float log_softabs_eps = logaddexp_f(log_softabs, LOG_DISC_EPS);
    float w = __expf(-log_softabs_eps * 0.125f);      // /N_DEG = /8

    float v1 = speed * w, v2 = sp2, v3 = ac2;
#pragma unroll
    for (int off = 32; off; off >>= 1) {
        v1 += __shfl_down(v1, off);
        v2 += __shfl_down(v2, off);
        v3 += __shfl_down(v3, off);
    }
    const int wid = tid >> 6, lane = tid & 63;
    if (lane == 0) { red[wid][0] = v1; red[wid][1] = v2; red[wid][2] = v3; }
    __syncthreads();
    if (tid == 0) {
        float s1 = 0.f, s2 = 0.f, s3 = 0.f;
        for (int w2 = 0; w2 < 4; ++w2) { s1 += red[w2][0]; s2 += red[w2][1]; s3 += red[w2][2]; }
        partial[blockIdx.x * 3 + 0] = s1;
        partial[blockIdx.x * 3 + 1] = s2;
        partial[blockIdx.x * 3 + 2] = s3;
    }
}

__global__ __launch_bounds__(NBLK) void bez_finalize_kernel(
    const float* __restrict__ partial, float* __restrict__ out)
{
    const int tid = threadIdx.x;
    float v1 = partial[tid * 3 + 0];
    float v2 = partial[tid * 3 + 1];
    float v3 = partial[tid * 3 + 2];
#pragma unroll
    for (int off = 32; off; off >>= 1) {
        v1 += __shfl_down(v1, off);
        v2 += __shfl_down(v2, off);
        v3 += __shfl_down(v3, off);
    }
    __shared__ float red[8][3];
    const int wid = tid >> 6, lane = tid & 63;
    if (lane == 0) { red[wid][0] = v1; red[wid][1] = v2; red[wid][2] = v3; }
    __syncthreads();
    if (tid == 0) {
        float s1 = 0.f, s2 = 0.f, s3 = 0.f;
        for (int w2 = 0; w2 < 8; ++w2) { s1 += red[w2][0]; s2 += red[w2][1]; s3 += red[w2][2]; }
        const float Mf = (float)M_SAMPLES;
        out[0] = s1 / Mf + 0.1f * sqrtf(s2 / Mf) + 0.01f * sqrtf(s3 / Mf);
    }
}

extern "C" void kernel_launch(void* const* d_in, const int* in_sizes, int n_in,
                              void* d_out, int out_size, void* d_ws, size_t ws_size,
                              hipStream_t stream) {
    const float* P0   = (const float*)d_in[0];   // (8,2)
    const float* Pd   = (const float*)d_in[1];   // (8,2)
    const float* Pmid = (const float*)d_in[2];   // (6,8,2)
    const float* ts   = (const float*)d_in[3];   // (131072,)
    float* out = (float*)d_out;
    float* partial = (float*)d_ws;               // NBLK*3 floats

    bez_main_kernel<<<NBLK, BLK, 0, stream>>>(P0, Pd, Pmid, ts, partial);
    bez_finalize_kernel<<<1, NBLK, 0, stream>>>(partial, out);
}